// Round 3
// baseline (205.371 us; speedup 1.0000x reference)
//
#include <hip/hip_runtime.h>
#include <stdint.h>

// Problem constants (B,H,W,C) = (8,128,128,64); out width = (W-1)+H = 255.
#define BB 8
#define HH 128
#define WW 128
#define CC 64
#define OUTW 255

// X staging: 128 rows of bf16, padded 64 -> 72 elems (144 B): keeps 16B
// alignment for ds_read_b128 and offsets consecutive rows by 4 banks.
#define LDS_STRIDE 72
// Pass-2 assembly strip: 32 output rows x 255 floats (contiguous slab quarter).
#define EPW 255

typedef __attribute__((ext_vector_type(8))) short bf16x8;   // 8 bf16 in 4 VGPRs
typedef __attribute__((ext_vector_type(4))) float f32x4;

__device__ __forceinline__ unsigned short f2bf(float f) {
    union { float f; uint32_t u; } v; v.f = f;
    uint32_t u = v.u;
    // round-to-nearest-even; inputs are finite normals
    return (unsigned short)((u + 0x7FFFu + ((u >> 16) & 1u)) >> 16);
}

// ---------------------------------------------------------------------------
// Pass 1: column grams. Block g = b*128 + j computes G_col(b,j)[i][m] =
// <x[b,i,j,:], x[b,m,j,:]> and stores it CONTIGUOUSLY at ws[b][j][i][m]
// (64 KB sequential per block — DRAM-friendly; read back by pass 2 from L3).
// ---------------------------------------------------------------------------
__global__ __launch_bounds__(256)
void cc_pass1_colgram(const float* __restrict__ x, float* __restrict__ ws) {
    __shared__ unsigned short xs[128 * LDS_STRIDE];   // 18432 B

    const int g = blockIdx.x;
    const int b = g >> 7;
    const int j = g & 127;
    const float* xbase = x + (size_t)(b * HH * WW + j) * CC;   // pixel (0, j)
    float* wbase = ws + (size_t)g * (128 * 128);
    const int t = threadIdx.x;

    // Stage column pixels (128 x 64 fp32, 32 KB stride between pixels) -> bf16 LDS.
    #pragma unroll
    for (int r = 0; r < 8; ++r) {
        const int idx = r * 256 + t;
        const int row = idx >> 4;
        const int c4  = (idx & 15) << 2;
        const float4 v = *(const float4*)(xbase + (size_t)row * (WW * CC) + c4);
        ushort4* dst = (ushort4*)&xs[row * LDS_STRIDE + c4];
        *dst = make_ushort4(f2bf(v.x), f2bf(v.y), f2bf(v.z), f2bf(v.w));
    }
    __syncthreads();

    const int wave = t >> 6;
    const int lane = t & 63;
    const int m16  = lane & 15;
    const int quad = lane >> 4;

    f32x4 acc[2][8];
    #pragma unroll
    for (int rt = 0; rt < 2; ++rt)
        #pragma unroll
        for (int ct = 0; ct < 8; ++ct)
            acc[rt][ct] = (f32x4){0.f, 0.f, 0.f, 0.f};

    #pragma unroll
    for (int ks = 0; ks < 2; ++ks) {
        const int kOff = ks * 32 + quad * 8;
        bf16x8 afrag[2];
        #pragma unroll
        for (int rt = 0; rt < 2; ++rt)
            afrag[rt] = *(const bf16x8*)&xs[(wave * 32 + rt * 16 + m16) * LDS_STRIDE + kOff];
        #pragma unroll
        for (int ct = 0; ct < 8; ++ct) {
            const bf16x8 bfrag = *(const bf16x8*)&xs[(ct * 16 + m16) * LDS_STRIDE + kOff];
            acc[0][ct] = __builtin_amdgcn_mfma_f32_16x16x32_bf16(afrag[0], bfrag, acc[0][ct], 0, 0, 0);
            acc[1][ct] = __builtin_amdgcn_mfma_f32_16x16x32_bf16(afrag[1], bfrag, acc[1][ct], 0, 0, 0);
        }
    }

    // Direct stores into the block's contiguous 64 KB region (L2 merges the
    // C-layout interleave; region-local so no cross-block partial lines).
    #pragma unroll
    for (int rt = 0; rt < 2; ++rt) {
        #pragma unroll
        for (int reg = 0; reg < 4; ++reg) {
            const int gm = wave * 32 + rt * 16 + quad * 4 + reg;
            float* rp = wbase + gm * 128;
            #pragma unroll
            for (int ct = 0; ct < 8; ++ct) {
                const int gn = ct * 16 + m16;
                __builtin_nontemporal_store(acc[rt][ct][reg], &rp[gn]);
            }
        }
    }
}

// ---------------------------------------------------------------------------
// Pass 2: block g = b*128 + i computes the row-gram of image row i, merges in
// the col-parts gathered from ws, and writes the ENTIRE output slab
// out[b,i,:,:] (130,560 B) as perfectly sequential, 16B-aligned float4 stores.
// Wave tiling: wave w owns G columns [32w, 32w+32) across ALL 128 rows, so
// every wave contributes to every 32-row assembly phase.
// ---------------------------------------------------------------------------
__global__ __launch_bounds__(256)
void cc_pass2_rowgram_merge(const float* __restrict__ x, const float* __restrict__ ws,
                            float* __restrict__ out) {
    __shared__ unsigned short xs[128 * LDS_STRIDE];   // 18432 B
    __shared__ float ep[32 * EPW];                    // 32640 B (slab quarter)

    const int g = blockIdx.x;
    const int b = g >> 7;
    const int i = g & 127;
    const float* xbase = x + (size_t)(b * HH + i) * WW * CC;   // row i, contiguous
    float* obase = out + (size_t)g * (WW * OUTW);              // slab, 16B-aligned
    const float* wsb = ws + (size_t)b * (128 * 128 * 128);
    const int t = threadIdx.x;

    // Stage row pixels (contiguous 32 KB) -> bf16 LDS.
    #pragma unroll
    for (int r = 0; r < 8; ++r) {
        const int idx = r * 256 + t;
        const int row = idx >> 4;
        const int c4  = (idx & 15) << 2;
        const float4 v = *(const float4*)(xbase + row * CC + c4);
        ushort4* dst = (ushort4*)&xs[row * LDS_STRIDE + c4];
        *dst = make_ushort4(f2bf(v.x), f2bf(v.y), f2bf(v.z), f2bf(v.w));
    }
    __syncthreads();

    const int wave = t >> 6;
    const int lane = t & 63;
    const int m16  = lane & 15;
    const int quad = lane >> 4;

    // acc[c][r]: row-tile r (G rows 16r..16r+15), col-subtile c (cols 32w+16c..+16)
    f32x4 acc[2][8];
    #pragma unroll
    for (int c = 0; c < 2; ++c)
        #pragma unroll
        for (int r = 0; r < 8; ++r)
            acc[c][r] = (f32x4){0.f, 0.f, 0.f, 0.f};

    #pragma unroll
    for (int ks = 0; ks < 2; ++ks) {
        const int kOff = ks * 32 + quad * 8;
        bf16x8 bfrag[2];
        #pragma unroll
        for (int c = 0; c < 2; ++c)
            bfrag[c] = *(const bf16x8*)&xs[(wave * 32 + c * 16 + m16) * LDS_STRIDE + kOff];
        #pragma unroll
        for (int r = 0; r < 8; ++r) {
            const bf16x8 afrag = *(const bf16x8*)&xs[(r * 16 + m16) * LDS_STRIDE + kOff];
            acc[0][r] = __builtin_amdgcn_mfma_f32_16x16x32_bf16(afrag, bfrag[0], acc[0][r], 0, 0, 0);
            acc[1][r] = __builtin_amdgcn_mfma_f32_16x16x32_bf16(afrag, bfrag[1], acc[1][r], 0, 0, 0);
        }
    }

    // 4 assembly phases: G rows (= output rows j) [32q, 32q+32).
    for (int q = 0; q < 4; ++q) {
        // (a) Row-part scatter with diagonal compaction. D layout: col=m16,
        //     row=quad*4+reg within the 16-row tile.
        #pragma unroll
        for (int rr = 0; rr < 2; ++rr) {
            const int r = 2 * q + rr;
            #pragma unroll
            for (int c = 0; c < 2; ++c) {
                const int n = wave * 32 + c * 16 + m16;   // G column
                #pragma unroll
                for (int reg = 0; reg < 4; ++reg) {
                    const int jl = rr * 16 + quad * 4 + reg;  // local row 0..31
                    const int ja = 32 * q + jl;               // output row j
                    if (n != ja)
                        ep[jl * EPW + (n - (n > ja ? 1 : 0))] = acc[c][r][reg];
                }
            }
        }
        // (b) Col-part gather from ws (L3-resident): thread t covers
        //     j = 32q + (t>>3), floats [16*(t&7), +16) -> ep[jl][127+...].
        {
            const int jl = t >> 3;
            const int ch = t & 7;
            const int ja = 32 * q + jl;
            const float4* src = (const float4*)(wsb + ((size_t)ja * 128 + i) * 128 + ch * 16);
            float* dst = &ep[jl * EPW + 127 + ch * 16];
            const float4 v0 = src[0], v1 = src[1], v2 = src[2], v3 = src[3];
            dst[0]=v0.x; dst[1]=v0.y; dst[2]=v0.z;  dst[3]=v0.w;
            dst[4]=v1.x; dst[5]=v1.y; dst[6]=v1.z;  dst[7]=v1.w;
            dst[8]=v2.x; dst[9]=v2.y; dst[10]=v2.z; dst[11]=v2.w;
            dst[12]=v3.x; dst[13]=v3.y; dst[14]=v3.z; dst[15]=v3.w;
        }
        __syncthreads();
        // (c) Stream the quarter out: 8160 floats = 2040 float4, contiguous,
        //     16B-aligned (slab base = g*130560 B, quarter = 32640 B).
        {
            const f32x4* eps = (const f32x4*)ep;
            f32x4* oq = (f32x4*)(obase + q * 32 * OUTW);
            #pragma unroll
            for (int s = 0; s < 8; ++s) {
                const int idx = t + 256 * s;
                if (idx < 2040)
                    __builtin_nontemporal_store(eps[idx], &oq[idx]);
            }
        }
        __syncthreads();
    }
}

extern "C" void kernel_launch(void* const* d_in, const int* in_sizes, int n_in,
                              void* d_out, int out_size, void* d_ws, size_t ws_size,
                              hipStream_t stream) {
    const float* x = (const float*)d_in[0];
    float* out = (float*)d_out;
    float* ws = (float*)d_ws;   // needs 8*128*128*128 floats = 67.1 MB
    cc_pass1_colgram<<<dim3(BB * WW), dim3(256), 0, stream>>>(x, ws);
    cc_pass2_rowgram_merge<<<dim3(BB * HH), dim3(256), 0, stream>>>(x, ws, out);
}

// Round 4
// 164.190 us; speedup vs baseline: 1.2508x; 1.2508x over previous
//
#include <hip/hip_runtime.h>
#include <stdint.h>

// Problem constants (B,H,W,C) = (8,128,128,64); out width = (W-1)+H = 255.
#define BB 8
#define HH 128
#define WW 128
#define CC 64
#define OUTW 255

// X staging: 128 rows of bf16, padded 64 -> 72 elems (144 B): keeps 16B
// alignment for ds_read_b128 and offsets consecutive rows by 4 banks.
#define LDS_STRIDE 72
// Epilogue staging: 16 rows x 130 floats per wave (wave-private strip).
#define EP_STRIDE 130

typedef __attribute__((ext_vector_type(8))) short bf16x8;   // 8 bf16 in 4 VGPRs
typedef __attribute__((ext_vector_type(4))) float f32x4;

__device__ __forceinline__ unsigned short f2bf(float f) {
    union { float f; uint32_t u; } v; v.f = f;
    uint32_t u = v.u;
    // round-to-nearest-even; inputs are finite normals
    return (unsigned short)((u + 0x7FFFu + ((u >> 16) & 1u)) >> 16);
}

// One block computes one 128x128 Gram matrix G = X * X^T, X = 128x64.
// Block mapping INTERLEAVES row- and col-gram blocks (g&1) so that all 256
// writers of one batch image's 16.7 MB output region are dispatched in one
// temporal window -> junction cache lines and DRAM pages of out[b,i,:,:] get
// written close in time (L2 merge, DRAM page locality).
__global__ __launch_bounds__(256)
void criss_cross_gram_kernel(const float* __restrict__ x, float* __restrict__ out) {
    __shared__ unsigned short xs[128 * LDS_STRIDE];       // 18432 B
    __shared__ float ep[4][16 * EP_STRIDE];               // 33280 B

    const int g = blockIdx.x;          // grid = 2048 = 8 * 256
    const int b = g >> 8;
    const int rem = g & 255;
    const bool isCol = (rem & 1);
    const int p = rem >> 1;            // i (row gram) or j (col gram)

    const float* xbase;
    int xRowStride;      // floats between consecutive X rows
    int outBase;         // float offset of G-row 0 in out
    int outRowStride;    // floats between consecutive G rows in out
    if (!isCol) {
        xbase        = x + ((b * HH + p) * WW) * CC;   // x[b,p,0,:]
        xRowStride   = CC;                              // row pixels contiguous
        outBase      = ((b * HH + p) * WW) * OUTW;      // out[b,p,j,*]
        outRowStride = OUTW;
    } else {
        xbase        = x + (b * HH * WW + p) * CC;      // x[b,0,p,:]
        xRowStride   = WW * CC;                         // column pixels strided
        outBase      = (b * HH * WW + p) * OUTW;        // out[b,i,p,127+*]
        outRowStride = WW * OUTW;
    }

    const int t = threadIdx.x;

    // ---- Stage X (128x64 fp32) into LDS as bf16. 2048 float4 loads total. ----
    #pragma unroll
    for (int r = 0; r < 8; ++r) {
        const int idx = r * 256 + t;        // 0..2047
        const int row = idx >> 4;           // 0..127
        const int c4  = (idx & 15) << 2;    // float4 column
        const float4 v = *(const float4*)(xbase + row * xRowStride + c4);
        ushort4* dst = (ushort4*)&xs[row * LDS_STRIDE + c4];
        *dst = make_ushort4(f2bf(v.x), f2bf(v.y), f2bf(v.z), f2bf(v.w));
    }
    __syncthreads();

    // ---- MFMA: wave w computes G rows [w*32, w*32+32) x all 128 cols. ----
    const int wave = t >> 6;
    const int lane = t & 63;
    const int m16  = lane & 15;
    const int quad = lane >> 4;

    f32x4 acc[2][8];
    #pragma unroll
    for (int rt = 0; rt < 2; ++rt)
        #pragma unroll
        for (int ct = 0; ct < 8; ++ct)
            acc[rt][ct] = (f32x4){0.f, 0.f, 0.f, 0.f};

    #pragma unroll
    for (int ks = 0; ks < 2; ++ks) {
        const int kOff = ks * 32 + quad * 8;
        bf16x8 afrag[2];
        #pragma unroll
        for (int rt = 0; rt < 2; ++rt) {
            const int row = wave * 32 + rt * 16 + m16;
            afrag[rt] = *(const bf16x8*)&xs[row * LDS_STRIDE + kOff];
        }
        #pragma unroll
        for (int ct = 0; ct < 8; ++ct) {
            const int row = ct * 16 + m16;
            const bf16x8 bfrag = *(const bf16x8*)&xs[row * LDS_STRIDE + kOff];
            acc[0][ct] = __builtin_amdgcn_mfma_f32_16x16x32_bf16(afrag[0], bfrag, acc[0][ct], 0, 0, 0);
            acc[1][ct] = __builtin_amdgcn_mfma_f32_16x16x32_bf16(afrag[1], bfrag, acc[1][ct], 0, 0, 0);
        }
    }

    // ---- Epilogue: wave-private LDS round-trip, then contiguous 256B stores.
    // No __syncthreads needed: ep[wave] is touched only by this wave; the
    // compiler orders same-wave ds_write -> ds_read via lgkmcnt.
    // C/D layout: col = lane&15, row = quad*4 + reg.
    float* myep = &ep[wave][0];

    #pragma unroll
    for (int rt = 0; rt < 2; ++rt) {
        const int rowBase = wave * 32 + rt * 16;

        // Scatter C fragments into LDS, applying diagonal compaction here
        // (cheap LDS predication instead of predicated global stores).
        #pragma unroll
        for (int ct = 0; ct < 8; ++ct) {
            #pragma unroll
            for (int reg = 0; reg < 4; ++reg) {
                const int rl = quad * 4 + reg;      // local row 0..15
                const int gm = rowBase + rl;
                const int gn = ct * 16 + m16;
                const float v = acc[rt][ct][reg];
                if (isCol) {
                    myep[rl * EP_STRIDE + gn] = v;
                } else if (gn != gm) {
                    myep[rl * EP_STRIDE + (gn - (gn > gm ? 1 : 0))] = v;
                }
            }
        }

        // Linear read-back + contiguous global stores: 2 x 256B per G-row.
        #pragma unroll
        for (int r = 0; r < 16; ++r) {
            float* rp = out + outBase + (rowBase + r) * outRowStride + (isCol ? 127 : 0);
            rp[lane] = myep[r * EP_STRIDE + lane];
            if (isCol || lane < 63)   // col: 64 floats, row: 63 floats in 2nd half
                rp[64 + lane] = myep[r * EP_STRIDE + 64 + lane];
        }
    }
}

extern "C" void kernel_launch(void* const* d_in, const int* in_sizes, int n_in,
                              void* d_out, int out_size, void* d_ws, size_t ws_size,
                              hipStream_t stream) {
    const float* x = (const float*)d_in[0];
    float* out = (float*)d_out;
    // 2048 blocks: interleaved row/col gram writers, one 128x128 Gram each.
    criss_cross_gram_kernel<<<dim3(BB * (HH + WW)), dim3(256), 0, stream>>>(x, out);
}